// Round 3
// baseline (1435.735 us; speedup 1.0000x reference)
//
#include <hip/hip_runtime.h>
#include <hip/hip_bf16.h>

// ConvTransE decoder, fused bf16-MFMA implementation, round 3.
//
//   scores[b] = sum_d ( sum_{f,p} relu(conv[b,f,p]) * fc[f*1022+p][d] + fc_bias[d] ) * obj_e[b][d]
//
// R3 changes vs R2 (R2: 334us gemm, MfmaUtil 37% == exactly the 132us MFMA
// floor -> all overhead is phase serialization + syncthreads drains):
//  - B double-buffered; per-iter: issue loads EARLY, drain LATE (one
//    vmcnt(0)+lgkm(0) after MFMA+A-gen), raw s_barriers (no __syncthreads
//    full-drain in the loop). T3/T4/T14 adapted for VALU-generated A.
//  - conv weights moved to SGPRs (wave-uniform A-gen roles via
//    readfirstlane) -> kills 64 ds_read_b32/thread/iter that could not be
//    hoisted across barriers. Each lane generates 2 rows x 8 filters.
//  - s_setprio(1) around the MFMA cluster (T5; phase-split now exists).
// LDS: B 2x32KB + A 16KB = 81920 B exactly -> 2 blocks/CU.
// ws layout: [0,32MiB) combined f32 (8192x1024); [32MiB,~64MiB) fcT bf16 (512x32704).

#define ND    512
#define NF    32
#define NP    1022
#define KTOT  32704      // NP*NF
#define NB    8192
#define BM    128
#define BN    256
#define BK    64
#define NSTEPS 511       // KTOT/BK

typedef __attribute__((ext_vector_type(8))) short bf16x8;
typedef __attribute__((ext_vector_type(4))) float f32x4;

typedef const __attribute__((address_space(1))) unsigned int* gas1_p;
typedef __attribute__((address_space(3))) unsigned int* las3_p;

__device__ __forceinline__ void gload_lds16(const void* g, const void* l) {
  // global -> LDS direct, 16B per lane. LDS dest is wave-uniform base + lane*16.
  __builtin_amdgcn_global_load_lds((gas1_p)(unsigned long long)(uintptr_t)g,
                                   (las3_p)(unsigned int)(uintptr_t)l, 16, 0, 0);
}

__device__ __forceinline__ unsigned int pack_bf16x2(float a, float b) {
  __hip_bfloat162 hh = __float22bfloat162_rn(make_float2(a, b));
  unsigned int u;
  __builtin_memcpy(&u, &hh, 4);
  return u;
}

// 8 relu'd conv outputs (one filter-quarter) packed to 4x bf16x2 words.
// Weight layout: W0..W5 = cw[24q .. 24q+23] (f-major, 3 taps per f);
// Bb0/Bb1 = cb[8q..8q+7].
__device__ __forceinline__ uint4 gen8(float tA, float tB, float tC,
    const float4& W0, const float4& W1, const float4& W2,
    const float4& W3, const float4& W4, const float4& W5,
    const float4& Bb0, const float4& Bb1) {
  float v0 = fmaxf(0.f, Bb0.x + W0.x * tA + W0.y * tB + W0.z * tC);
  float v1 = fmaxf(0.f, Bb0.y + W0.w * tA + W1.x * tB + W1.y * tC);
  float v2 = fmaxf(0.f, Bb0.z + W1.z * tA + W1.w * tB + W2.x * tC);
  float v3 = fmaxf(0.f, Bb0.w + W2.y * tA + W2.z * tB + W2.w * tC);
  float v4 = fmaxf(0.f, Bb1.x + W3.x * tA + W3.y * tB + W3.z * tC);
  float v5 = fmaxf(0.f, Bb1.y + W3.w * tA + W4.x * tB + W4.y * tC);
  float v6 = fmaxf(0.f, Bb1.z + W4.z * tA + W4.w * tB + W5.x * tC);
  float v7 = fmaxf(0.f, Bb1.w + W5.y * tA + W5.z * tB + W5.w * tC);
  uint4 w;
  w.x = pack_bf16x2(v0, v1); w.y = pack_bf16x2(v2, v3);
  w.z = pack_bf16x2(v4, v5); w.w = pack_bf16x2(v6, v7);
  return w;
}

// ---------------- K1: gather combined = [subj_e | rel_e] ----------------
__global__ __launch_bounds__(256) void k_gather(const float* __restrict__ ent,
                                                const float* __restrict__ rel,
                                                const int* __restrict__ trip,
                                                float* __restrict__ comb) {
  int b = blockIdx.x, t = threadIdx.x;
  int s = trip[b * 3 + 0], r = trip[b * 3 + 1];
  float4 v;
  if (t < 128) v = ((const float4*)(ent + (size_t)s * ND))[t];
  else         v = ((const float4*)(rel + (size_t)r * ND))[t - 128];
  ((float4*)(comb + (size_t)b * 1024))[t] = v;
}

// ---------------- K2: fcT[d][p*32+f] = (bf16) fc[f*1022+p][d] ----------------
__global__ __launch_bounds__(256) void k_fcT(const float* __restrict__ fc,
                                             unsigned short* __restrict__ fcT) {
  __shared__ float tile[32][132];   // [f][d-local], padded (132%32=4) for column reads
  int p = blockIdx.x >> 2, dt = blockIdx.x & 3;
  int d0 = dt * 128, t = threadIdx.x;
  int f = t >> 3, l8 = t & 7;
  const float* src = fc + ((size_t)f * NP + p) * ND + d0 + l8 * 16;
#pragma unroll
  for (int j = 0; j < 4; ++j) {
    float4 v = *(const float4*)(src + j * 4);
    *(float4*)&tile[f][l8 * 16 + j * 4] = v;
  }
  __syncthreads();
  if (t < 128) {
    unsigned int outw[16];
#pragma unroll
    for (int fq = 0; fq < 16; ++fq)
      outw[fq] = pack_bf16x2(tile[2 * fq][t], tile[2 * fq + 1][t]);
    unsigned short* dst = fcT + (size_t)(d0 + t) * KTOT + p * NF;  // 64B aligned
#pragma unroll
    for (int i = 0; i < 4; ++i) {
      uint4 w;
      w.x = outw[i * 4 + 0]; w.y = outw[i * 4 + 1];
      w.z = outw[i * 4 + 2]; w.w = outw[i * 4 + 3];
      *(uint4*)((char*)dst + i * 16) = w;
    }
  }
}

// ---------------- K3: fused GEMM + obj-dot epilogue ----------------
// grid = 512: xcd = bid&7 = n_blk*4 + ksp; m_blk = bid>>3 (64).
// 8 waves (2x4 MFMA grid, wave tile 64x64, acc 4x4), split-K=4.
// A-gen roles: wave wv -> (q = wv&3 filter-quarter, h = wv>>2 pos-half);
// lane covers rows {lane, lane+64}.
__global__ __launch_bounds__(512, 4) void k_gemm(
    const float* __restrict__ comb, const unsigned short* __restrict__ fcT,
    const float* __restrict__ cw, const float* __restrict__ cb,
    const float* __restrict__ fcb, const int* __restrict__ trip,
    const float* __restrict__ ent, float* __restrict__ out) {
  __shared__ unsigned short Bl[2][BN * BK];  // 2 x 32 KB, XOR-swizzled via source
  __shared__ unsigned short Al[BM * BK];     // 16 KB, swizzled: slot ^= (row&7)

  const int tid = threadIdx.x;
  const int bid = blockIdx.x;
  const int xcd = bid & 7;
  const int n_blk = xcd >> 2, ksp = xcd & 3, m_blk = bid >> 3;

  const int wv = tid >> 6, lane = tid & 63;
  const int wm = wv >> 2, wn = wv & 3;          // MFMA wave grid 2x4
  const int r16 = lane & 15, rq = lane >> 4;

  // ---- A-gen role + weights into scalar regs (wave-uniform address)
  const int q = wv & 3, h = wv >> 2;
  const int qu = __builtin_amdgcn_readfirstlane(q);
  const float4* wp = (const float4*)(cw + qu * 24);
  const float4 W0 = wp[0], W1 = wp[1], W2 = wp[2], W3 = wp[3], W4 = wp[4], W5 = wp[5];
  const float4* bp = (const float4*)(cb + qu * 8);
  const float4 Bb0 = bp[0], Bb1 = bp[1];
  const int word = h * 4 + q;                   // 16B word index within a 128B A row

  const int r0 = lane, r1 = lane + 64;
  const float* crow0 = comb + (size_t)(m_blk * BM + r0) * 1024;
  const float* crow1 = comb + (size_t)(m_blk * BM + r1) * 1024;

  f32x4 acc[4][4];
#pragma unroll
  for (int i = 0; i < 4; ++i)
#pragma unroll
    for (int j = 0; j < 4; ++j)
      acc[i][j] = (f32x4)0.0f;

  const int sb = (NSTEPS * ksp) >> 2;           // {0,127,255,383}
  const int se = (NSTEPS * (ksp + 1)) >> 2;     // {127,255,383,511}

  // ---- prologue: c-window regs, A(sb), B(sb)
  float2 p01a = *(const float2*)(crow0 + 2 * sb);
  float2 p23a = *(const float2*)(crow0 + 2 * sb + 2);
  float2 p45a = *(const float2*)(crow0 + 2 * sb + 4);
  float2 p01b = *(const float2*)(crow1 + 2 * sb);
  float2 p23b = *(const float2*)(crow1 + 2 * sb + 2);
  float2 p45b = *(const float2*)(crow1 + 2 * sb + 4);

  {
    const int k0 = sb * BK;
#pragma unroll
    for (int r = 0; r < 4; ++r) {
      int c = r * 512 + tid;
      int dl = c >> 3, kq = c & 7, kqs = kq ^ (dl & 7);
      const unsigned short* src =
          fcT + (size_t)(n_blk * BN + dl) * KTOT + (k0 + kqs * 8);
      gload_lds16(src, &Bl[sb & 1][0] + (size_t)(r * 512 + wv * 64) * 8);
    }
  }
  {
    // gen A(sb): taps for pos 2*sb+h
    float tA0 = h ? p01a.y : p01a.x, tB0 = h ? p23a.x : p01a.y, tC0 = h ? p23a.y : p23a.x;
    float tA1 = h ? p01b.y : p01b.x, tB1 = h ? p23b.x : p01b.y, tC1 = h ? p23b.y : p23b.x;
    uint4 wA = gen8(tA0, tB0, tC0, W0, W1, W2, W3, W4, W5, Bb0, Bb1);
    uint4 wB = gen8(tA1, tB1, tC1, W0, W1, W2, W3, W4, W5, Bb0, Bb1);
    *(uint4*)((char*)Al + r0 * 128 + ((word ^ (r0 & 7)) * 16)) = wA;
    *(uint4*)((char*)Al + r1 * 128 + ((word ^ (r1 & 7)) * 16)) = wB;
  }
  // window for gen A(sb+1): comb[2(sb+1) .. 2(sb+1)+3]
  float ac0 = p23a.x, ac1 = p23a.y, ac2 = p45a.x, ac3 = p45a.y;
  float bc0 = p23b.x, bc1 = p23b.y, bc2 = p45b.x, bc3 = p45b.y;

  __syncthreads();   // prologue full drain: B(sb) landed, A(sb) visible

  for (int s = sb; s < se; ++s) {
    const int cur = s & 1, nxt = cur ^ 1;
    const bool more = (s + 1 < se);

    // ---- c-prefetch for gen A(s+2), issued FIRST so later compiler waits
    // on these don't drain the B gloads behind them
    float2 ea, eb;
    if (s + 2 < se) {
      ea = *(const float2*)(crow0 + 2 * s + 6);
      eb = *(const float2*)(crow1 + 2 * s + 6);
    }
    __builtin_amdgcn_sched_barrier(0);

    // ---- issue B(s+1) stage (stays in flight across both barriers)
    if (more) {
      const int k0 = (s + 1) * BK;
#pragma unroll
      for (int r = 0; r < 4; ++r) {
        int c = r * 512 + tid;
        int dl = c >> 3, kq = c & 7, kqs = kq ^ (dl & 7);
        const unsigned short* src =
            fcT + (size_t)(n_blk * BN + dl) * KTOT + (k0 + kqs * 8);
        gload_lds16(src, &Bl[nxt][0] + (size_t)(r * 512 + wv * 64) * 8);
      }
    }

    // ---- fragment reads (swizzled) + MFMA on current buffers
    const char* BlC = (const char*)&Bl[cur][0];
    bf16x8 af[4][2], bfr[4][2];
#pragma unroll
    for (int mi = 0; mi < 4; ++mi) {
      int row = wm * 64 + mi * 16 + r16;
#pragma unroll
      for (int ks = 0; ks < 2; ++ks) {
        int slot = (ks * 4 + rq) ^ (row & 7);
        af[mi][ks] = *(const bf16x8*)((const char*)Al + row * 128 + slot * 16);
      }
    }
#pragma unroll
    for (int ni = 0; ni < 4; ++ni) {
      int dl = wn * 64 + ni * 16 + r16;
#pragma unroll
      for (int ks = 0; ks < 2; ++ks) {
        int slot = (ks * 4 + rq) ^ (dl & 7);
        bfr[ni][ks] = *(const bf16x8*)(BlC + dl * 128 + slot * 16);
      }
    }
    __builtin_amdgcn_s_setprio(1);
#pragma unroll
    for (int ks = 0; ks < 2; ++ks)
#pragma unroll
      for (int mi = 0; mi < 4; ++mi)
#pragma unroll
        for (int ni = 0; ni < 4; ++ni)
          acc[mi][ni] = __builtin_amdgcn_mfma_f32_16x16x32_bf16(
              af[mi][ks], bfr[ni][ks], acc[mi][ni], 0, 0, 0);
    __builtin_amdgcn_s_setprio(0);

    __builtin_amdgcn_sched_barrier(0);
    __builtin_amdgcn_s_barrier();     // B1: all waves done reading Al / Bl[cur]

    // ---- generate A(s+1) into Al (single-buffered, protected by B1/B2)
    if (more) {
      float tA0 = h ? ac1 : ac0, tB0 = h ? ac2 : ac1, tC0 = h ? ac3 : ac2;
      float tA1 = h ? bc1 : bc0, tB1 = h ? bc2 : bc1, tC1 = h ? bc3 : bc2;
      uint4 wA = gen8(tA0, tB0, tC0, W0, W1, W2, W3, W4, W5, Bb0, Bb1);
      uint4 wB = gen8(tA1, tB1, tC1, W0, W1, W2, W3, W4, W5, Bb0, Bb1);
      *(uint4*)((char*)Al + r0 * 128 + ((word ^ (r0 & 7)) * 16)) = wA;
      *(uint4*)((char*)Al + r1 * 128 + ((word ^ (r1 & 7)) * 16)) = wB;
      if (s + 2 < se) {
        ac0 = ac2; ac1 = ac3; ac2 = ea.x; ac3 = ea.y;
        bc0 = bc2; bc1 = bc3; bc2 = eb.x; bc3 = eb.y;
      }
    }

    // ---- single late drain: own B gloads + c loads retired, ds_writes visible
    asm volatile("s_waitcnt vmcnt(0) lgkmcnt(0)" ::: "memory");
    __builtin_amdgcn_sched_barrier(0);
    __builtin_amdgcn_s_barrier();     // B2: next iter may read Al / Bl[nxt]
  }

  // ---- epilogue: scores[b] += sum_d (proj + fc_bias) * obj_e[b][d]
  // C/D layout (m89-verified): col = lane&15, row = (lane>>4)*4 + reg.
  const int colbase = n_blk * BN + wn * 64;
#pragma unroll
  for (int mi = 0; mi < 4; ++mi) {
#pragma unroll
    for (int rr = 0; rr < 4; ++rr) {
      int row = m_blk * BM + wm * 64 + mi * 16 + rq * 4 + rr;
      int oid = trip[row * 3 + 2];
      const float* orow = ent + (size_t)oid * ND + colbase;
      float part = 0.f;
#pragma unroll
      for (int ni = 0; ni < 4; ++ni) {
        int d = ni * 16 + r16;
        float v = acc[mi][ni][rr];
        if (ksp == 0) v += fcb[colbase + d];   // add bias exactly once per (b,d)
        part += v * orow[d];
      }
      part += __shfl_xor(part, 1);
      part += __shfl_xor(part, 2);
      part += __shfl_xor(part, 4);
      part += __shfl_xor(part, 8);
      if (r16 == 0) atomicAdd(out + row, part);
    }
  }
}

extern "C" void kernel_launch(void* const* d_in, const int* in_sizes, int n_in,
                              void* d_out, int out_size, void* d_ws, size_t ws_size,
                              hipStream_t stream) {
  const float* ent = (const float*)d_in[0];
  const float* rel = (const float*)d_in[1];
  const float* cw  = (const float*)d_in[2];
  const float* cb  = (const float*)d_in[3];
  const float* fc  = (const float*)d_in[4];
  const float* fcb = (const float*)d_in[5];
  const int*   trp = (const int*)d_in[6];
  float* out = (float*)d_out;

  float* comb = (float*)d_ws;                                        // 32 MiB
  unsigned short* fcT = (unsigned short*)((char*)d_ws + (size_t)NB * 1024 * 4);

  hipMemsetAsync(d_out, 0, (size_t)out_size * sizeof(float), stream);
  k_gather<<<NB, 256, 0, stream>>>(ent, rel, trp, comb);
  k_fcT<<<NP * 4, 256, 0, stream>>>(fc, fcT);
  k_gemm<<<512, 512, 0, stream>>>(comb, fcT, cw, cb, fcb, trp, ent, out);
}